// Round 11
// baseline (3265.459 us; speedup 1.0000x reference)
//
#include <hip/hip_runtime.h>
#include <hip/hip_bf16.h>

typedef __hip_bfloat16 bf16;

// B=8, T=8192, D=64, M=256, chunk L=64, NCHUNK=1024, NTOK=65536
#define NEED_WS_BYTES 110625024ULL

__device__ __forceinline__ float b2f(bf16 x) { return __bfloat162float(x); }
__device__ __forceinline__ bf16  f2b(float x) { return __float2bfloat16(x); }
__device__ __forceinline__ float bflo(unsigned u) { return __uint_as_float(u << 16); }
__device__ __forceinline__ float bfhi(unsigned u) { return __uint_as_float(u & 0xffff0000u); }
// pack two floats as bf16 pair: low half = a, high half = b
__device__ __forceinline__ unsigned pack2(float a, float b) {
  bf16 ba = f2b(a), bb = f2b(b);
  unsigned short ua = *reinterpret_cast<unsigned short*>(&ba);
  unsigned short ub = *reinterpret_cast<unsigned short*>(&bb);
  return ((unsigned)ub << 16) | (unsigned)ua;
}

// dtype-dispatched input load: isf32 ? f32 : bf16
__device__ __forceinline__ float ldin(const void* p, size_t i, int isf32) {
  return isf32 ? ((const float*)p)[i] : b2f(((const bf16*)p)[i]);
}

// ---- k_detect: decide whether inputs are f32 or bf16 -----------------------
__global__ __launch_bounds__(256) void k_detect(const void* __restrict__ q,
                                                int* __restrict__ flag) {
  __shared__ int cnt;
  if (threadIdx.x == 0) cnt = 0;
  __syncthreads();
  const unsigned short* u = (const unsigned short*)q;
  int c = 0;
  for (int e = threadIdx.x; e < 2048; e += 256) {
    unsigned short w = u[2 * e];
    int ex = (w >> 7) & 0xFF;
    if ((w & 0x7FFF) != 0 && (ex < 110 || ex > 140)) c++;
  }
  atomicAdd(&cnt, c);
  __syncthreads();
  if (threadIdx.x == 0) *flag = (cnt > 512) ? 1 : 0;
}

// ---- k_phi: phi = exp(dot - rowmax(dot))/16, bf16 out ----------------------
// (-0.5||x||^2 cancels exactly under the rowmax subtraction; omitted.)
// grid (1024, 2) x 256: block = one 64-token chunk; y=0 -> phiQ, y=1 -> phiK.
// R11: omega row held PACKED bf16 (32 uints, not 64 floats) -> live set ~95-114
// -> fits a 128-reg budget -> waves_per_eu(4,4): max=4 forbids the 8-wave
// squeeze (R6: 64 regs, spill), min=4 pins budget at 128 which now fits
// (R7 failed only because live was ~160 > 128). Target: 16 waves/CU.
// SPILL HISTORY: R5 none->spill; R6 lb(256,4)->64reg spill; R7 waves(2,4)->
// 128reg spill (f32 om too big); R8 waves(1,2)->256reg OK but 8 waves/CU,
// 390us; R9 waves(1,4)->52reg spill. Tripwire: FETCH>100MB on k_phi = spill.
__global__ __launch_bounds__(256)
__attribute__((amdgpu_waves_per_eu(4, 4))) void k_phi(
    const void* __restrict__ q, const void* __restrict__ k,
    const void* __restrict__ omega, bf16* __restrict__ phiQ,
    bf16* __restrict__ phiK, const int* __restrict__ flag) {
  __shared__ float xs[64 * 68];   // [t][d] pad 68: staging writes conflict-free
  __shared__ float wred[8 * 4];   // per-token per-wave maxes (8-token group)
  int isf32 = *flag;
  int tid = threadIdx.x;
  int isK = blockIdx.y;
  const void* src = isK ? k : q;
  bf16* dst = isK ? phiK : phiQ;
  size_t tok0 = (size_t)blockIdx.x * 64;

  for (int e = tid; e < 4096; e += 256) {
    int t = e >> 6, d = e & 63;
    xs[t * 68 + d] = ldin(src, tok0 * 64 + e, isf32) * 0.125f;
  }
  // omega row j -> 32 packed bf16 regs (64 KB global, L2-hot)
  unsigned omp[32];
  if (isf32) {
    const float4* orow = (const float4*)((const float*)omega + tid * 64);
    #pragma unroll
    for (int i4 = 0; i4 < 16; ++i4) {
      float4 r = orow[i4];
      omp[i4 * 2 + 0] = pack2(r.x, r.y);
      omp[i4 * 2 + 1] = pack2(r.z, r.w);
    }
  } else {
    const uint2* orow = (const uint2*)((const bf16*)omega + tid * 64);
    #pragma unroll
    for (int i4 = 0; i4 < 16; ++i4) {
      uint2 u = orow[i4];
      omp[i4 * 2 + 0] = u.x;
      omp[i4 * 2 + 1] = u.y;
    }
  }
  __syncthreads();

  int lane = tid & 63, w = tid >> 6;
  for (int grp = 0; grp < 8; ++grp) {
    float lp[8];
    #pragma unroll
    for (int tt = 0; tt < 8; ++tt) {
      const float4* xr = (const float4*)(xs + (grp * 8 + tt) * 68);
      float dot = 0.f;
      #pragma unroll
      for (int i4 = 0; i4 < 16; ++i4) {
        float4 xv = xr[i4];   // same addr all lanes -> LDS broadcast
        unsigned u0 = omp[i4 * 2], u1 = omp[i4 * 2 + 1];
        dot += bflo(u0) * xv.x + bfhi(u0) * xv.y +
               bflo(u1) * xv.z + bfhi(u1) * xv.w;
      }
      lp[tt] = dot;
    }
    #pragma unroll
    for (int tt = 0; tt < 8; ++tt) {
      float m = lp[tt];
      #pragma unroll
      for (int off = 32; off; off >>= 1) m = fmaxf(m, __shfl_xor(m, off, 64));
      if (lane == 0) wred[tt * 4 + w] = m;
    }
    __syncthreads();
    #pragma unroll
    for (int tt = 0; tt < 8; ++tt) {
      const float4 mr = *(const float4*)(wred + tt * 4);
      float mx = fmaxf(fmaxf(mr.x, mr.y), fmaxf(mr.z, mr.w));
      size_t n = tok0 + grp * 8 + tt;
      dst[n * 256 + tid] = f2b(__expf(lp[tt] - mx) * 0.0625f);  // 1/sqrt(256)
    }
    __syncthreads();
  }
}

// ---- k_slocal: per-chunk S (m x d) bf16 and z f32 --------------------------
__global__ __launch_bounds__(256) void k_slocal(
    const bf16* __restrict__ phiK, const void* __restrict__ v,
    bf16* __restrict__ Sloc, float* __restrict__ zloc,
    const int* __restrict__ flag) {
  __shared__ float vs[64 * 64];
  int isf32 = *flag;
  int chunk = blockIdx.x;
  size_t tok0 = (size_t)chunk * 64;
  int tid = threadIdx.x;
  for (int e = tid; e < 4096; e += 256) vs[e] = ldin(v, tok0 * 64 + e, isf32);
  __syncthreads();
  int i = tid;
  float acc[64];
  #pragma unroll
  for (int jj = 0; jj < 64; ++jj) acc[jj] = 0.f;
  float az = 0.f;
  #pragma unroll 2
  for (int t = 0; t < 64; ++t) {
    float pk = b2f(phiK[(tok0 + t) * 256 + i]);
    az += pk;
    const float* vr = vs + t * 64;
    #pragma unroll
    for (int jj = 0; jj < 64; ++jj) acc[jj] += pk * vr[jj];
  }
  bf16* Sr = Sloc + ((size_t)chunk * 256 + i) * 64;
  #pragma unroll
  for (int jj = 0; jj < 64; ++jj) Sr[jj] = f2b(acc[jj]);
  zloc[(size_t)chunk * 256 + i] = az;
}

// ---- k_sprefix: in-place exclusive prefix of Sloc over chunks (bf16) -------
__global__ __launch_bounds__(64) void k_sprefix(bf16* __restrict__ Sloc) {
  int b = blockIdx.x >> 8, i = blockIdx.x & 255;
  int d = threadIdx.x;
  size_t base = (size_t)b * 2097152 + (size_t)i * 64 + d;
  float vbuf[128];
  #pragma unroll
  for (int c = 0; c < 128; ++c) vbuf[c] = b2f(Sloc[base + (size_t)c * 16384]);
  float run = 0.f;
  #pragma unroll
  for (int c = 0; c < 128; ++c) { float t = vbuf[c]; vbuf[c] = run; run += t; }
  #pragma unroll
  for (int c = 0; c < 128; ++c) Sloc[base + (size_t)c * 16384] = f2b(vbuf[c]);
}

// ---- k_zprefix: in-place exclusive prefix of zloc over chunks (f32) --------
__global__ __launch_bounds__(64) void k_zprefix(float* __restrict__ zloc) {
  int b = blockIdx.x >> 2, ig = blockIdx.x & 3;
  int i = ig * 64 + threadIdx.x;
  size_t base = (size_t)b * 32768 + i;
  float vbuf[128];
  #pragma unroll
  for (int c = 0; c < 128; ++c) vbuf[c] = zloc[base + (size_t)c * 256];
  float run = 0.f;
  #pragma unroll
  for (int c = 0; c < 128; ++c) { float t = vbuf[c]; vbuf[c] = run; run += t; }
  #pragma unroll
  for (int c = 0; c < 128; ++c) zloc[base + (size_t)c * 256] = vbuf[c];
}

// ---- k_outA: AT[tau][t] = sum_i pq[t][i]*pk[tau][i], bf16 to global --------
__global__ __launch_bounds__(256) void k_outA(
    const bf16* __restrict__ phiQ, const bf16* __restrict__ phiK,
    bf16* __restrict__ ATg) {
  __shared__ bf16 pqTs[256 * 68];   // [i][t]  34.8 KB
  __shared__ bf16 pkTs[256 * 68];   // [i][tau] 34.8 KB  -> 2 blocks/CU
  int chunk = blockIdx.x;
  size_t tok0 = (size_t)chunk * 64;
  int tid = threadIdx.x;
  int t = tid & 63;
  int g = __builtin_amdgcn_readfirstlane(tid >> 6);

  for (int e = tid; e < 16384; e += 256) {
    int tt = e >> 8, i = e & 255;        // i lane-consecutive: coalesced reads
    pqTs[i * 68 + tt] = phiQ[(tok0 + tt) * 256 + i];
    pkTs[i * 68 + tt] = phiK[(tok0 + tt) * 256 + i];
  }
  __syncthreads();

  float a[16];
  #pragma unroll
  for (int jj = 0; jj < 16; ++jj) a[jj] = 0.f;
  #pragma unroll 2
  for (int i = 0; i < 256; ++i) {
    float pq = b2f(pqTs[i * 68 + t]);
    const uint2* pkv = (const uint2*)(pkTs + i * 68 + g * 16);  // 8B-aligned
    #pragma unroll
    for (int u = 0; u < 4; ++u) {
      uint2 p4 = pkv[u];   // 4 bf16, uniform addr -> LDS b64 broadcast
      a[u * 4 + 0] += pq * bflo(p4.x);
      a[u * 4 + 1] += pq * bfhi(p4.x);
      a[u * 4 + 2] += pq * bflo(p4.y);
      a[u * 4 + 3] += pq * bfhi(p4.y);
    }
  }
  bf16* arow = ATg + (size_t)chunk * 4096;
  #pragma unroll
  for (int jj = 0; jj < 16; ++jj)
    arow[(g * 16 + jj) * 64 + t] = f2b(a[jj]);   // lanes t consec: coalesced
}

// ---- k_outB: out[t] = (pq@Sp + tril(A)@V) / (pq.zp + rowsum(tril A) + eps) -
__global__ __launch_bounds__(256) void k_outB(
    const bf16* __restrict__ phiQ, const void* __restrict__ v,
    const bf16* __restrict__ Sloc, const float* __restrict__ zloc,
    const bf16* __restrict__ ATg, void* __restrict__ outp,
    const int* __restrict__ flag) {
  __shared__ bf16 pqTs[256 * 68];   // [i][t]
  __shared__ float vs[64 * 64];
  int isf32 = *flag;
  int chunk = blockIdx.x;
  size_t tok0 = (size_t)chunk * 64;
  int tid = threadIdx.x;
  int t = tid & 63;
  int g = __builtin_amdgcn_readfirstlane(tid >> 6);

  for (int e = tid; e < 16384; e += 256) {
    int tt = e >> 8, i = e & 255;
    pqTs[i * 68 + tt] = phiQ[(tok0 + tt) * 256 + i];
  }
  for (int e = tid; e < 4096; e += 256) vs[e] = ldin(v, tok0 * 64 + e, isf32);
  __syncthreads();

  // phase 1: out1 = pq @ Sp ; den = pq . zp   (Sp/zp wave-uniform loads)
  float acc1[16];
  #pragma unroll
  for (int jj = 0; jj < 16; ++jj) acc1[jj] = 0.f;
  float den = 0.f;
  const bf16* Srow0 = Sloc + (size_t)chunk * 16384 + g * 16;
  const float* zp = zloc + (size_t)chunk * 256;
  #pragma unroll 2
  for (int i = 0; i < 256; ++i) {
    float pq = b2f(pqTs[i * 68 + t]);
    const bf16* sp = Srow0 + i * 64;
    #pragma unroll
    for (int jj = 0; jj < 16; ++jj) acc1[jj] += pq * b2f(sp[jj]);
    den += pq * zp[i];
  }

  // phase 2: out2 = tril(A) @ V ; den += rowsum(tril A)
  float acc2[16];
  #pragma unroll
  for (int jj = 0; jj < 16; ++jj) acc2[jj] = 0.f;
  const bf16* arow = ATg + (size_t)chunk * 4096;
  for (int tau = 0; tau < 64; ++tau) {
    float av = b2f(arow[tau * 64 + t]);   // lanes t consec: coalesced, L2-hot
    av = (tau <= t) ? av : 0.f;
    den += av;
    const float* vr = vs + tau * 64 + g * 16;
    #pragma unroll
    for (int jj = 0; jj < 16; ++jj) acc2[jj] += av * vr[jj];
  }

  float r = 1.f / (den + 1e-6f);
  size_t obase = (tok0 + t) * 64 + g * 16;
  if (isf32) {
    float* orow = (float*)outp + obase;
    #pragma unroll
    for (int jj = 0; jj < 16; ++jj) orow[jj] = (acc1[jj] + acc2[jj]) * r;
  } else {
    bf16* orow = (bf16*)outp + obase;
    #pragma unroll
    for (int jj = 0; jj < 16; ++jj) orow[jj] = f2b((acc1[jj] + acc2[jj]) * r);
  }
}

extern "C" void kernel_launch(void* const* d_in, const int* in_sizes, int n_in,
                              void* d_out, int out_size, void* d_ws, size_t ws_size,
                              hipStream_t stream) {
  (void)in_sizes; (void)n_in; (void)out_size;
  if (ws_size < NEED_WS_BYTES) return;   // diagnostic guard (absmax==3.859375)

  const void* q = d_in[0];
  const void* k = d_in[1];
  const void* v = d_in[2];
  const void* omega = d_in[3];

  int*   flag = (int*)d_ws;
  float* wsf  = (float*)d_ws + 64;       // data starts 256 B in
  float* zloc = wsf + 131072;            // 1024*256 f32
  bf16*  Sloc = (bf16*)(wsf + 393216);   // 1024*256*64 bf16
  bf16*  phiQ = (bf16*)(wsf + 8781824);  // 65536*256 bf16
  bf16*  phiK = (bf16*)(wsf + 17170432); // 65536*256 bf16
  bf16*  ATg  = (bf16*)(wsf + 25559040); // 1024*64*64 bf16 (4.2M elems)
  // total = (64 + 25559040 + 2097152) * 4 = 110,625,024 B

  k_detect<<<1, 256, 0, stream>>>(q, flag);
  k_phi<<<dim3(1024, 2), 256, 0, stream>>>(q, k, omega, phiQ, phiK, flag);
  k_slocal<<<1024, 256, 0, stream>>>(phiK, v, Sloc, zloc, flag);
  k_sprefix<<<2048, 64, 0, stream>>>(Sloc);
  k_zprefix<<<32, 64, 0, stream>>>(zloc);
  k_outA<<<1024, 256, 0, stream>>>(phiQ, phiK, ATg);
  k_outB<<<1024, 256, 0, stream>>>(phiQ, v, Sloc, zloc, ATg, d_out, flag);
}

// Round 12
// 430.161 us; speedup vs baseline: 7.5912x; 7.5912x over previous
//
#include <hip/hip_runtime.h>
#include <hip/hip_bf16.h>

typedef __hip_bfloat16 bf16;
typedef __attribute__((ext_vector_type(8))) short short8;   // 8 bf16, 4 VGPRs
typedef __attribute__((ext_vector_type(4))) float floatx4;  // MFMA acc

// B=8, T=8192, D=64, M=256, chunk L=64, NCHUNK=1024, NTOK=65536
#define NEED_WS_BYTES 110625024ULL

__device__ __forceinline__ float b2f(bf16 x) { return __bfloat162float(x); }
__device__ __forceinline__ bf16  f2b(float x) { return __float2bfloat16(x); }
__device__ __forceinline__ float bflo(unsigned u) { return __uint_as_float(u << 16); }
__device__ __forceinline__ float bfhi(unsigned u) { return __uint_as_float(u & 0xffff0000u); }

// dtype-dispatched input load: isf32 ? f32 : bf16
__device__ __forceinline__ float ldin(const void* p, size_t i, int isf32) {
  return isf32 ? ((const float*)p)[i] : b2f(((const bf16*)p)[i]);
}

// ---- k_detect: decide whether inputs are f32 or bf16 -----------------------
__global__ __launch_bounds__(256) void k_detect(const void* __restrict__ q,
                                                int* __restrict__ flag) {
  __shared__ int cnt;
  if (threadIdx.x == 0) cnt = 0;
  __syncthreads();
  const unsigned short* u = (const unsigned short*)q;
  int c = 0;
  for (int e = threadIdx.x; e < 2048; e += 256) {
    unsigned short w = u[2 * e];
    int ex = (w >> 7) & 0xFF;
    if ((w & 0x7FFF) != 0 && (ex < 110 || ex > 140)) c++;
  }
  atomicAdd(&cnt, c);
  __syncthreads();
  if (threadIdx.x == 0) *flag = (cnt > 512) ? 1 : 0;
}

// ---- k_omega: convert omega -> bf16 copy (R11 showed bf16-omega is exact
// enough: absmax unchanged). 16384 elems, one-time. --------------------------
__global__ __launch_bounds__(256) void k_omega(const void* __restrict__ omega,
                                               bf16* __restrict__ omb,
                                               const int* __restrict__ flag) {
  int isf32 = *flag;
  int e = blockIdx.x * 256 + threadIdx.x;
  omb[e] = f2b(ldin(omega, e, isf32));
}

// ---- k_phi (MFMA): dot = x@omega^T via mfma_f32_16x16x32_bf16 --------------
// (-0.5||x||^2 cancels exactly under the rowmax subtraction; omitted.)
// grid (1024, 2) x 256 (4 waves): wave w -> tokens m0=w*16, all 256 features.
// Per wave: 16 tiles (n0) x 2 K-halves = 32 MFMA. Acc c[16][4]/lane; NO
// omega array in registers -> no spill fight. Layouts (m89/m91-verified):
//   A[m=lane&15][k=quad*8+j], B[n=lane&15][k=quad*8+j],
//   C: col=lane&15, row=quad*4+reg.
// SPILL LESSON (R5-R11): amdgpu_waves_per_eu max>2 => allocator demotes big
// arrays to scratch to chase occupancy. waves(1,2) is the only safe setting
// for >64-reg live sets. Tripwire: k_phi FETCH > 200 MB = spill = revert.
__global__ __launch_bounds__(256)
__attribute__((amdgpu_waves_per_eu(1, 2))) void k_phi(
    const void* __restrict__ q, const void* __restrict__ k,
    const bf16* __restrict__ omb, bf16* __restrict__ phiQ,
    bf16* __restrict__ phiK, const int* __restrict__ flag) {
  __shared__ short xb[64 * 72];   // x*0.125 bf16, row stride 72 (144 B, 16B-aligned)
  int isf32 = *flag;
  int tid = threadIdx.x;
  int isK = blockIdx.y;
  const void* src = isK ? k : q;
  bf16* dst = isK ? phiK : phiQ;
  size_t tok0 = (size_t)blockIdx.x * 64;

  // stage: lanes cover d=0..63 of one token per wave-iteration -> conflict-free
  for (int e = tid; e < 4096; e += 256) {
    int t = e >> 6, d = e & 63;
    bf16 h = f2b(ldin(src, tok0 * 64 + e, isf32) * 0.125f);
    xb[t * 72 + d] = *reinterpret_cast<short*>(&h);
  }
  __syncthreads();

  int li = tid & 15;
  int quad = (tid >> 4) & 3;
  int m0 = (tid >> 6) * 16;       // wave's token block

  // A fragments (K-halves 0/1): x[m0+li][quad*8 + j (+32)]
  short8 a0 = *reinterpret_cast<const short8*>(&xb[(m0 + li) * 72 + quad * 8]);
  short8 a1 = *reinterpret_cast<const short8*>(&xb[(m0 + li) * 72 + 32 + quad * 8]);

  floatx4 c[16];
  #pragma unroll
  for (int n0 = 0; n0 < 16; ++n0) {
    // B fragments: omega_bf16[n0*16+li][quad*8 + j (+32)]  (L2-hot, 16 B/lane)
    const short* bp = (const short*)omb + (size_t)(n0 * 16 + li) * 64 + quad * 8;
    short8 b0 = *reinterpret_cast<const short8*>(bp);
    short8 b1 = *reinterpret_cast<const short8*>(bp + 32);
    floatx4 acc = {0.f, 0.f, 0.f, 0.f};
    acc = __builtin_amdgcn_mfma_f32_16x16x32_bf16(a0, b0, acc, 0, 0, 0);
    acc = __builtin_amdgcn_mfma_f32_16x16x32_bf16(a1, b1, acc, 0, 0, 0);
    c[n0] = acc;
  }

  // rowmax over the 256 features of each of this lane's 4 rows:
  // local max over 16 tiles, then butterfly over the quad's 16 lanes.
  float mx[4];
  #pragma unroll
  for (int r = 0; r < 4; ++r) {
    float m = c[0][r];
    #pragma unroll
    for (int n0 = 1; n0 < 16; ++n0) m = fmaxf(m, c[n0][r]);
    mx[r] = m;
  }
  #pragma unroll
  for (int mask = 1; mask < 16; mask <<= 1) {
    #pragma unroll
    for (int r = 0; r < 4; ++r) mx[r] = fmaxf(mx[r], __shfl_xor(mx[r], mask, 64));
  }

  // phi = exp(dot - rowmax)/16; store row (tok0+m0+quad*4+r), col n0*16+li
  #pragma unroll
  for (int r = 0; r < 4; ++r) {
    size_t n = tok0 + m0 + quad * 4 + r;
    bf16* drow = dst + n * 256 + li;
    #pragma unroll
    for (int n0 = 0; n0 < 16; ++n0)
      drow[n0 * 16] = f2b(__expf(c[n0][r] - mx[r]) * 0.0625f);  // 1/sqrt(256)
  }
}

// ---- k_slocal: per-chunk S (m x d) bf16 and z f32 --------------------------
__global__ __launch_bounds__(256) void k_slocal(
    const bf16* __restrict__ phiK, const void* __restrict__ v,
    bf16* __restrict__ Sloc, float* __restrict__ zloc,
    const int* __restrict__ flag) {
  __shared__ float vs[64 * 64];
  int isf32 = *flag;
  int chunk = blockIdx.x;
  size_t tok0 = (size_t)chunk * 64;
  int tid = threadIdx.x;
  for (int e = tid; e < 4096; e += 256) vs[e] = ldin(v, tok0 * 64 + e, isf32);
  __syncthreads();
  int i = tid;
  float acc[64];
  #pragma unroll
  for (int jj = 0; jj < 64; ++jj) acc[jj] = 0.f;
  float az = 0.f;
  #pragma unroll 2
  for (int t = 0; t < 64; ++t) {
    float pk = b2f(phiK[(tok0 + t) * 256 + i]);
    az += pk;
    const float* vr = vs + t * 64;
    #pragma unroll
    for (int jj = 0; jj < 64; ++jj) acc[jj] += pk * vr[jj];
  }
  bf16* Sr = Sloc + ((size_t)chunk * 256 + i) * 64;
  #pragma unroll
  for (int jj = 0; jj < 64; ++jj) Sr[jj] = f2b(acc[jj]);
  zloc[(size_t)chunk * 256 + i] = az;
}

// ---- k_sprefix: in-place exclusive prefix of Sloc over chunks (bf16) -------
__global__ __launch_bounds__(64) void k_sprefix(bf16* __restrict__ Sloc) {
  int b = blockIdx.x >> 8, i = blockIdx.x & 255;
  int d = threadIdx.x;
  size_t base = (size_t)b * 2097152 + (size_t)i * 64 + d;
  float vbuf[128];
  #pragma unroll
  for (int c = 0; c < 128; ++c) vbuf[c] = b2f(Sloc[base + (size_t)c * 16384]);
  float run = 0.f;
  #pragma unroll
  for (int c = 0; c < 128; ++c) { float t = vbuf[c]; vbuf[c] = run; run += t; }
  #pragma unroll
  for (int c = 0; c < 128; ++c) Sloc[base + (size_t)c * 16384] = f2b(vbuf[c]);
}

// ---- k_zprefix: in-place exclusive prefix of zloc over chunks (f32) --------
__global__ __launch_bounds__(64) void k_zprefix(float* __restrict__ zloc) {
  int b = blockIdx.x >> 2, ig = blockIdx.x & 3;
  int i = ig * 64 + threadIdx.x;
  size_t base = (size_t)b * 32768 + i;
  float vbuf[128];
  #pragma unroll
  for (int c = 0; c < 128; ++c) vbuf[c] = zloc[base + (size_t)c * 256];
  float run = 0.f;
  #pragma unroll
  for (int c = 0; c < 128; ++c) { float t = vbuf[c]; vbuf[c] = run; run += t; }
  #pragma unroll
  for (int c = 0; c < 128; ++c) zloc[base + (size_t)c * 256] = vbuf[c];
}

// ---- k_outA: AT[tau][t] = sum_i pq[t][i]*pk[tau][i], bf16 to global --------
__global__ __launch_bounds__(256) void k_outA(
    const bf16* __restrict__ phiQ, const bf16* __restrict__ phiK,
    bf16* __restrict__ ATg) {
  __shared__ bf16 pqTs[256 * 68];   // [i][t]  34.8 KB
  __shared__ bf16 pkTs[256 * 68];   // [i][tau] 34.8 KB  -> 2 blocks/CU
  int chunk = blockIdx.x;
  size_t tok0 = (size_t)chunk * 64;
  int tid = threadIdx.x;
  int t = tid & 63;
  int g = __builtin_amdgcn_readfirstlane(tid >> 6);

  for (int e = tid; e < 16384; e += 256) {
    int tt = e >> 8, i = e & 255;        // i lane-consecutive: coalesced reads
    pqTs[i * 68 + tt] = phiQ[(tok0 + tt) * 256 + i];
    pkTs[i * 68 + tt] = phiK[(tok0 + tt) * 256 + i];
  }
  __syncthreads();

  float a[16];
  #pragma unroll
  for (int jj = 0; jj < 16; ++jj) a[jj] = 0.f;
  #pragma unroll 2
  for (int i = 0; i < 256; ++i) {
    float pq = b2f(pqTs[i * 68 + t]);
    const uint2* pkv = (const uint2*)(pkTs + i * 68 + g * 16);  // 8B-aligned
    #pragma unroll
    for (int u = 0; u < 4; ++u) {
      uint2 p4 = pkv[u];   // 4 bf16, uniform addr -> LDS b64 broadcast
      a[u * 4 + 0] += pq * bflo(p4.x);
      a[u * 4 + 1] += pq * bfhi(p4.x);
      a[u * 4 + 2] += pq * bflo(p4.y);
      a[u * 4 + 3] += pq * bfhi(p4.y);
    }
  }
  bf16* arow = ATg + (size_t)chunk * 4096;
  #pragma unroll
  for (int jj = 0; jj < 16; ++jj)
    arow[(g * 16 + jj) * 64 + t] = f2b(a[jj]);   // lanes t consec: coalesced
}

// ---- k_outB: out[t] = (pq@Sp + tril(A)@V) / (pq.zp + rowsum(tril A) + eps) -
__global__ __launch_bounds__(256) void k_outB(
    const bf16* __restrict__ phiQ, const void* __restrict__ v,
    const bf16* __restrict__ Sloc, const float* __restrict__ zloc,
    const bf16* __restrict__ ATg, void* __restrict__ outp,
    const int* __restrict__ flag) {
  __shared__ bf16 pqTs[256 * 68];   // [i][t]
  __shared__ float vs[64 * 64];
  int isf32 = *flag;
  int chunk = blockIdx.x;
  size_t tok0 = (size_t)chunk * 64;
  int tid = threadIdx.x;
  int t = tid & 63;
  int g = __builtin_amdgcn_readfirstlane(tid >> 6);

  for (int e = tid; e < 16384; e += 256) {
    int tt = e >> 8, i = e & 255;
    pqTs[i * 68 + tt] = phiQ[(tok0 + tt) * 256 + i];
  }
  for (int e = tid; e < 4096; e += 256) vs[e] = ldin(v, tok0 * 64 + e, isf32);
  __syncthreads();

  // phase 1: out1 = pq @ Sp ; den = pq . zp   (Sp/zp wave-uniform loads)
  float acc1[16];
  #pragma unroll
  for (int jj = 0; jj < 16; ++jj) acc1[jj] = 0.f;
  float den = 0.f;
  const bf16* Srow0 = Sloc + (size_t)chunk * 16384 + g * 16;
  const float* zp = zloc + (size_t)chunk * 256;
  #pragma unroll 2
  for (int i = 0; i < 256; ++i) {
    float pq = b2f(pqTs[i * 68 + t]);
    const bf16* sp = Srow0 + i * 64;
    #pragma unroll
    for (int jj = 0; jj < 16; ++jj) acc1[jj] += pq * b2f(sp[jj]);
    den += pq * zp[i];
  }

  // phase 2: out2 = tril(A) @ V ; den += rowsum(tril A)
  float acc2[16];
  #pragma unroll
  for (int jj = 0; jj < 16; ++jj) acc2[jj] = 0.f;
  const bf16* arow = ATg + (size_t)chunk * 4096;
  for (int tau = 0; tau < 64; ++tau) {
    float av = b2f(arow[tau * 64 + t]);   // lanes t consec: coalesced, L2-hot
    av = (tau <= t) ? av : 0.f;
    den += av;
    const float* vr = vs + tau * 64 + g * 16;
    #pragma unroll
    for (int jj = 0; jj < 16; ++jj) acc2[jj] += av * vr[jj];
  }

  float r = 1.f / (den + 1e-6f);
  size_t obase = (tok0 + t) * 64 + g * 16;
  if (isf32) {
    float* orow = (float*)outp + obase;
    #pragma unroll
    for (int jj = 0; jj < 16; ++jj) orow[jj] = (acc1[jj] + acc2[jj]) * r;
  } else {
    bf16* orow = (bf16*)outp + obase;
    #pragma unroll
    for (int jj = 0; jj < 16; ++jj) orow[jj] = f2b((acc1[jj] + acc2[jj]) * r);
  }
}

extern "C" void kernel_launch(void* const* d_in, const int* in_sizes, int n_in,
                              void* d_out, int out_size, void* d_ws, size_t ws_size,
                              hipStream_t stream) {
  (void)in_sizes; (void)n_in; (void)out_size;
  if (ws_size < NEED_WS_BYTES) return;   // diagnostic guard (absmax==3.859375)

  const void* q = d_in[0];
  const void* k = d_in[1];
  const void* v = d_in[2];
  const void* omega = d_in[3];

  int*   flag = (int*)d_ws;
  float* wsf  = (float*)d_ws + 64;       // data starts 256 B in
  bf16*  omb  = (bf16*)wsf;              // 16384 bf16 in the unused hn hole
  float* zloc = wsf + 131072;            // 1024*256 f32
  bf16*  Sloc = (bf16*)(wsf + 393216);   // 1024*256*64 bf16
  bf16*  phiQ = (bf16*)(wsf + 8781824);  // 65536*256 bf16
  bf16*  phiK = (bf16*)(wsf + 17170432); // 65536*256 bf16
  bf16*  ATg  = (bf16*)(wsf + 25559040); // 1024*64*64 bf16
  // total = (64 + 25559040 + 2097152) * 4 = 110,625,024 B

  k_detect<<<1, 256, 0, stream>>>(q, flag);
  k_omega<<<64, 256, 0, stream>>>(omega, omb, flag);
  k_phi<<<dim3(1024, 2), 256, 0, stream>>>(q, k, omb, phiQ, phiK, flag);
  k_slocal<<<1024, 256, 0, stream>>>(phiK, v, Sloc, zloc, flag);
  k_sprefix<<<2048, 64, 0, stream>>>(Sloc);
  k_zprefix<<<32, 64, 0, stream>>>(zloc);
  k_outA<<<1024, 256, 0, stream>>>(phiQ, phiK, ATg);
  k_outB<<<1024, 256, 0, stream>>>(phiQ, v, Sloc, zloc, ATg, d_out, flag);
}